// Round 2
// baseline (706.333 us; speedup 1.0000x reference)
//
#include <hip/hip_runtime.h>
#include <cstdint>
#include <cstddef>

typedef __attribute__((ext_vector_type(8))) unsigned short us8;

#define B_ 4
#define C_ 384
#define H_ 224
#define W_ 224
#define HH 28
#define WW 28
#define HW_ (H_*W_)
#define M_ (HH*WW)
#define SCALE_ 0.05103103630798288f   // 1/sqrt(384)
#define EPS_ 1e-12f

__device__ __forceinline__ unsigned short f2bf(float f) {
    union { float f; unsigned int u; } v; v.f = f;
    unsigned int r = v.u + 0x7FFFu + ((v.u >> 16) & 1u);
    return (unsigned short)(r >> 16);
}
__device__ __forceinline__ float bf2f(unsigned short h) {
    union { unsigned int u; float f; } v; v.u = ((unsigned int)h) << 16;
    return v.f;
}

// ---------------------------------------------------------------------------
// k_tp: layout transform + pool. Block = (b, py, cgroup of 16 channels).
// Reads x rows fully coalesced; LDS-transposes to patch-major; writes
// pix[b][m][l][c] bf16 (32B chunks, sector-aligned) and pooled stoken fp32.
// LDS patch stride 1032 ushorts: 2064B = 16B-aligned, bank stride 516%32=4.
// ---------------------------------------------------------------------------
__global__ __launch_bounds__(512) void k_tp(const float* __restrict__ x,
                                            unsigned short* __restrict__ pix,
                                            float* __restrict__ stoken) {
    int bid = blockIdx.x;
    int cg = bid % 24; int t2 = bid / 24; int py = t2 % HH; int b = t2 / HH;
    int c0 = cg * 16;
    int tid = threadIdx.x;
    __shared__ unsigned short lt[28 * 1032];

    for (int c = 0; c < 16; ++c) {
        const float* xb = x + ((size_t)(b * C_ + c0 + c) * H_ + py * 8) * W_;
        for (int i = tid; i < 8 * W_; i += 512) {
            int pp = i / W_;
            int w = i - pp * W_;
            int pxx = w >> 3, qq = w & 7;
            lt[pxx * 1032 + (pp * 8 + qq) * 16 + c] = f2bf(xb[i]);
        }
    }
    __syncthreads();

    // pool: mean over 64 pixels per (pxx, c)
    if (tid < 448) {
        int pxx = tid >> 4, c = tid & 15;
        const unsigned short* s = &lt[pxx * 1032 + c];
        float sum = 0.f;
        #pragma unroll
        for (int l = 0; l < 64; ++l) sum += bf2f(s[l * 16]);
        stoken[((size_t)b * M_ + py * WW + pxx) * C_ + c0 + c] = sum * (1.f / 64.f);
    }

    // write pix: per (pxx,l) a 32B chunk of 16 bf16 channels
    for (int j = tid; j < 28 * 64; j += 512) {
        int pxx = j >> 6, l = j & 63;
        const us8* s = (const us8*)&lt[pxx * 1032 + l * 16];
        us8 a0 = s[0], a1 = s[1];
        us8* d = (us8*)(pix + (((size_t)b * M_ + py * WW + pxx) * 64 + l) * C_ + c0);
        d[0] = a0; d[1] = a1;
    }
}

// ---------------------------------------------------------------------------
// k_it0: iteration 0. Block per (b, patch). stub fp32 in LDS; QK via per-lane
// contiguous us8 pixel loads; cross-wave LDS reduce; softmax; per-patch
// st_part[9][c] + normpart written non-atomically (folded by k_fold).
// ---------------------------------------------------------------------------
__global__ __launch_bounds__(256) void k_it0(const unsigned short* __restrict__ pix,
                                             const float* __restrict__ stoken,
                                             float* __restrict__ st_part,
                                             float* __restrict__ normpart) {
    int bid = blockIdx.x;
    int m = bid % M_, b = bid / M_;
    int py = m / WW, pxx = m - py * WW;
    int tid = threadIdx.x;
    int l = tid & 63, cg = tid >> 6, c0 = cg * 96;

    __shared__ float stub[9][C_];
    __shared__ float qkred[256][9];
    __shared__ float aff[64][10];

    for (int idx = tid; idx < 9 * C_; idx += 256) {
        int n = idx / C_, c = idx - n * C_;
        int yy = py + n / 3 - 1, xx = pxx + n % 3 - 1;
        float v = 0.f;
        if (yy >= 0 && yy < HH && xx >= 0 && xx < WW)
            v = stoken[((size_t)b * M_ + yy * WW + xx) * C_ + c];
        stub[n][c] = v;
    }
    __syncthreads();

    const unsigned short* prow = pix + (((size_t)b * M_ + m) * 64 + l) * C_;
    float acc[9];
    #pragma unroll
    for (int n = 0; n < 9; ++n) acc[n] = 0.f;
    for (int cc = c0; cc < c0 + 96; cc += 8) {
        us8 v = *(const us8*)(prow + cc);
        #pragma unroll
        for (int j = 0; j < 8; ++j) {
            float pv = bf2f(v[j]);
            #pragma unroll
            for (int n = 0; n < 9; ++n) acc[n] += pv * stub[n][cc + j];
        }
    }
    #pragma unroll
    for (int n = 0; n < 9; ++n) qkred[tid][n] = acc[n];
    __syncthreads();

    if (tid < 64) {
        float s[9];
        #pragma unroll
        for (int n = 0; n < 9; ++n)
            s[n] = (qkred[tid][n] + qkred[64 + tid][n] +
                    qkred[128 + tid][n] + qkred[192 + tid][n]) * SCALE_;
        float mx = s[0];
        #pragma unroll
        for (int n = 1; n < 9; ++n) mx = fmaxf(mx, s[n]);
        float den = 0.f;
        #pragma unroll
        for (int n = 0; n < 9; ++n) { float e = __expf(s[n] - mx); den += e; s[n] = e; }
        float inv = 1.f / den;
        #pragma unroll
        for (int n = 0; n < 9; ++n) aff[tid][n] = s[n] * inv;
    }
    __syncthreads();

    if (tid >= 64 && tid < 73) {
        int n = tid - 64;
        float s = 0.f;
        for (int ll = 0; ll < 64; ++ll) s += aff[ll][n];
        normpart[((size_t)b * M_ + m) * 9 + n] = s;
    }

    // phase 2: st[c][n] = sum_l pix[l][c]*aff[l][n]  (pix re-read from L2)
    const unsigned short* pbase = pix + (((size_t)b * M_ + m) * 64) * C_;
    for (int c = tid; c < C_; c += 256) {
        float a2[9];
        #pragma unroll
        for (int n = 0; n < 9; ++n) a2[n] = 0.f;
        for (int ll = 0; ll < 64; ++ll) {
            float pv = bf2f(pbase[(size_t)ll * C_ + c]);
            #pragma unroll
            for (int n = 0; n < 9; ++n) a2[n] += pv * aff[ll][n];
        }
        #pragma unroll
        for (int n = 0; n < 9; ++n)
            st_part[(((size_t)b * M_ + m) * 9 + n) * C_ + c] = a2[n];
    }
}

// ---------------------------------------------------------------------------
// k_fold: gather-fold st_part into refined stokens, pre-divided by fold-norm.
// Block per (b, cell). refined = (sum of valid neighbor contributions)/(norm+eps).
// ---------------------------------------------------------------------------
__global__ __launch_bounds__(256) void k_fold(const float* __restrict__ st_part,
                                              const float* __restrict__ normpart,
                                              float* __restrict__ refined) {
    int bid = blockIdx.x;
    int cell = bid % M_, b = bid / M_;
    int cy = cell / WW, cx = cell - cy * WW;
    int tid = threadIdx.x;

    float nsum = 0.f;
    int srcm[9]; int nsrc = 0;
    #pragma unroll
    for (int n = 0; n < 9; ++n) {
        int my = cy - (n / 3 - 1), mx = cx - (n % 3 - 1);
        if (my >= 0 && my < HH && mx >= 0 && mx < WW) {
            int mm = my * WW + mx;
            srcm[nsrc] = mm * 9 + n;
            nsum += normpart[(size_t)b * M_ * 9 + mm * 9 + n];
            ++nsrc;
        }
    }
    float inv = 1.f / (nsum + EPS_);
    for (int c = tid; c < C_; c += 256) {
        float s = 0.f;
        for (int k = 0; k < nsrc; ++k)
            s += st_part[((size_t)b * M_ * 9 + srcm[k]) * C_ + c];
        refined[((size_t)b * M_ + cell) * C_ + c] = s * inv;
    }
}

// ---------------------------------------------------------------------------
// k_fin: iteration 1 affinity + broadcast. Block per (b, patch).
// stub = refined (already normalized). out[c][l] = sum_n stub[n][c]*aff[l][n].
// ---------------------------------------------------------------------------
__global__ __launch_bounds__(256) void k_fin(const unsigned short* __restrict__ pix,
                                             const float* __restrict__ refined,
                                             float* __restrict__ out) {
    int bid = blockIdx.x;
    int m = bid % M_, b = bid / M_;
    int py = m / WW, pxx = m - py * WW;
    int tid = threadIdx.x;
    int l = tid & 63, cg = tid >> 6, c0 = cg * 96;

    __shared__ float stub[9][C_];
    __shared__ float qkred[256][9];
    __shared__ float aff[64][10];

    for (int idx = tid; idx < 9 * C_; idx += 256) {
        int n = idx / C_, c = idx - n * C_;
        int yy = py + n / 3 - 1, xx = pxx + n % 3 - 1;
        float v = 0.f;
        if (yy >= 0 && yy < HH && xx >= 0 && xx < WW)
            v = refined[((size_t)b * M_ + yy * WW + xx) * C_ + c];
        stub[n][c] = v;
    }
    __syncthreads();

    const unsigned short* prow = pix + (((size_t)b * M_ + m) * 64 + l) * C_;
    float acc[9];
    #pragma unroll
    for (int n = 0; n < 9; ++n) acc[n] = 0.f;
    for (int cc = c0; cc < c0 + 96; cc += 8) {
        us8 v = *(const us8*)(prow + cc);
        #pragma unroll
        for (int j = 0; j < 8; ++j) {
            float pv = bf2f(v[j]);
            #pragma unroll
            for (int n = 0; n < 9; ++n) acc[n] += pv * stub[n][cc + j];
        }
    }
    #pragma unroll
    for (int n = 0; n < 9; ++n) qkred[tid][n] = acc[n];
    __syncthreads();

    if (tid < 64) {
        float s[9];
        #pragma unroll
        for (int n = 0; n < 9; ++n)
            s[n] = (qkred[tid][n] + qkred[64 + tid][n] +
                    qkred[128 + tid][n] + qkred[192 + tid][n]) * SCALE_;
        float mx = s[0];
        #pragma unroll
        for (int n = 1; n < 9; ++n) mx = fmaxf(mx, s[n]);
        float den = 0.f;
        #pragma unroll
        for (int n = 0; n < 9; ++n) { float e = __expf(s[n] - mx); den += e; s[n] = e; }
        float inv = 1.f / den;
        #pragma unroll
        for (int n = 0; n < 9; ++n) aff[tid][n] = s[n] * inv;
    }
    __syncthreads();

    float areg[9];
    #pragma unroll
    for (int n = 0; n < 9; ++n) areg[n] = aff[l][n];
    float* obase = out + (size_t)b * C_ * HW_ + (size_t)(py * 8 + (l >> 3)) * W_ + pxx * 8 + (l & 7);
    for (int c = c0; c < c0 + 96; ++c) {
        float v = 0.f;
        #pragma unroll
        for (int n = 0; n < 9; ++n) v += stub[n][c] * areg[n];
        obase[(size_t)c * HW_] = v;
    }
}

// ===========================================================================
// Fallback path (round-1 kernels) if ws_size is too small for pix buffer.
// ===========================================================================
__global__ __launch_bounds__(256) void o_pool(const float* __restrict__ x,
                                              float* __restrict__ stoken) {
    int bid = blockIdx.x;
    int yy = bid % HH;
    int t  = bid / HH;
    int c  = t % C_;
    int b  = t / C_;
    __shared__ float colsum[W_];
    int q = threadIdx.x;
    if (q < W_) {
        const float* base = x + ((size_t)(b * C_ + c) * H_ + yy * 8) * W_ + q;
        float s = 0.f;
        #pragma unroll
        for (int p = 0; p < 8; ++p) s += base[(size_t)p * W_];
        colsum[q] = s;
    }
    __syncthreads();
    if (q < WW) {
        float s = 0.f;
        #pragma unroll
        for (int j = 0; j < 8; ++j) s += colsum[q * 8 + j];
        stoken[(((size_t)b * HH + yy) * WW + q) * C_ + c] = s * (1.f / 64.f);
    }
}

__global__ __launch_bounds__(256) void o_iter0(const float* __restrict__ x,
                                               const float* __restrict__ stoken,
                                               float* __restrict__ raw,
                                               float* __restrict__ norm) {
    int bid = blockIdx.x;
    int m = bid % M_;
    int b = bid / M_;
    int py = m / WW, pxx = m % WW;
    int tid = threadIdx.x;
    int w = tid >> 6, l = tid & 63;
    int pp = l >> 3, qq = l & 7;

    __shared__ unsigned short pixs[C_][66];
    __shared__ float sbuf[2304];
    __shared__ float aff[64][10];
    unsigned short* stub = (unsigned short*)sbuf;

    for (int idx = tid; idx < 9 * C_; idx += 256) {
        int n = idx / C_, c = idx - n * C_;
        int yy = py + n / 3 - 1, xx = pxx + n % 3 - 1;
        float v = 0.f;
        if (yy >= 0 && yy < HH && xx >= 0 && xx < WW)
            v = stoken[(((size_t)b * HH + yy) * WW + xx) * C_ + c];
        stub[idx] = f2bf(v);
    }
    __syncthreads();

    const float* pxbase = x + (size_t)b * C_ * HW_ + (size_t)(py * 8 + pp) * W_ + (pxx * 8 + qq);
    float acc[9];
    #pragma unroll
    for (int n = 0; n < 9; ++n) acc[n] = 0.f;
    int c0 = w * 96;
    #pragma unroll 4
    for (int c = c0; c < c0 + 96; ++c) {
        float pv = pxbase[(size_t)c * HW_];
        pixs[c][l] = f2bf(pv);
        #pragma unroll
        for (int n = 0; n < 9; ++n) acc[n] += pv * bf2f(stub[n * C_ + c]);
    }
    __syncthreads();
    float* qkred = sbuf;
    #pragma unroll
    for (int n = 0; n < 9; ++n) qkred[tid * 9 + n] = acc[n];
    __syncthreads();

    if (tid < 64) {
        float s[9];
        #pragma unroll
        for (int n = 0; n < 9; ++n)
            s[n] = (qkred[(0 * 64 + tid) * 9 + n] + qkred[(1 * 64 + tid) * 9 + n] +
                    qkred[(2 * 64 + tid) * 9 + n] + qkred[(3 * 64 + tid) * 9 + n]) * SCALE_;
        float mx = s[0];
        #pragma unroll
        for (int n = 1; n < 9; ++n) mx = fmaxf(mx, s[n]);
        float den = 0.f;
        #pragma unroll
        for (int n = 0; n < 9; ++n) { float e = __expf(s[n] - mx); den += e; s[n] = e; }
        float inv = 1.f / den;
        #pragma unroll
        for (int n = 0; n < 9; ++n) aff[tid][n] = s[n] * inv;
    }
    __syncthreads();

    if (tid < 9) {
        float s = 0.f;
        for (int ll = 0; ll < 64; ++ll) s += aff[ll][tid];
        int ty = py + tid / 3 - 1, tx = pxx + tid % 3 - 1;
        if (ty >= 0 && ty < HH && tx >= 0 && tx < WW)
            atomicAdd(&norm[((size_t)b * HH + ty) * WW + tx], s);
    }

    for (int c = tid; c < C_; c += 256) {
        float a2[9];
        #pragma unroll
        for (int n = 0; n < 9; ++n) a2[n] = 0.f;
        for (int ll = 0; ll < 64; ++ll) {
            float pv = bf2f(pixs[c][ll]);
            #pragma unroll
            for (int n = 0; n < 9; ++n) a2[n] += pv * aff[ll][n];
        }
        #pragma unroll
        for (int n = 0; n < 9; ++n) {
            int ty = py + n / 3 - 1, tx = pxx + n % 3 - 1;
            if (ty >= 0 && ty < HH && tx >= 0 && tx < WW)
                atomicAdd(&raw[(((size_t)b * HH + ty) * WW + tx) * C_ + c], a2[n]);
        }
    }
}

__global__ __launch_bounds__(256) void o_final(const float* __restrict__ x,
                                               const float* __restrict__ raw,
                                               const float* __restrict__ norm,
                                               float* __restrict__ out) {
    int bid = blockIdx.x;
    int m = bid % M_;
    int b = bid / M_;
    int py = m / WW, pxx = m % WW;
    int tid = threadIdx.x;
    int w = tid >> 6, l = tid & 63;
    int pp = l >> 3, qq = l & 7;

    __shared__ unsigned short stub[9 * C_];
    __shared__ float qkred[4 * 64 * 9];
    __shared__ float aff[64][10];

    for (int idx = tid; idx < 9 * C_; idx += 256) {
        int n = idx / C_, c = idx - n * C_;
        int yy = py + n / 3 - 1, xx = pxx + n % 3 - 1;
        float v = 0.f;
        if (yy >= 0 && yy < HH && xx >= 0 && xx < WW) {
            size_t cell = ((size_t)b * HH + yy) * WW + xx;
            v = raw[cell * C_ + c] / (norm[cell] + EPS_);
        }
        stub[idx] = f2bf(v);
    }
    __syncthreads();

    const float* pxbase = x + (size_t)b * C_ * HW_ + (size_t)(py * 8 + pp) * W_ + (pxx * 8 + qq);
    float acc[9];
    #pragma unroll
    for (int n = 0; n < 9; ++n) acc[n] = 0.f;
    int c0 = w * 96;
    #pragma unroll 4
    for (int c = c0; c < c0 + 96; ++c) {
        float pv = pxbase[(size_t)c * HW_];
        #pragma unroll
        for (int n = 0; n < 9; ++n) acc[n] += pv * bf2f(stub[n * C_ + c]);
    }
    #pragma unroll
    for (int n = 0; n < 9; ++n) qkred[tid * 9 + n] = acc[n];
    __syncthreads();

    if (tid < 64) {
        float s[9];
        #pragma unroll
        for (int n = 0; n < 9; ++n)
            s[n] = (qkred[(0 * 64 + tid) * 9 + n] + qkred[(1 * 64 + tid) * 9 + n] +
                    qkred[(2 * 64 + tid) * 9 + n] + qkred[(3 * 64 + tid) * 9 + n]) * SCALE_;
        float mx = s[0];
        #pragma unroll
        for (int n = 1; n < 9; ++n) mx = fmaxf(mx, s[n]);
        float den = 0.f;
        #pragma unroll
        for (int n = 0; n < 9; ++n) { float e = __expf(s[n] - mx); den += e; s[n] = e; }
        float inv = 1.f / den;
        #pragma unroll
        for (int n = 0; n < 9; ++n) aff[tid][n] = s[n] * inv;
    }
    __syncthreads();

    float areg[9];
    #pragma unroll
    for (int n = 0; n < 9; ++n) areg[n] = aff[l][n];
    float* obase = out + (size_t)b * C_ * HW_ + (size_t)(py * 8 + pp) * W_ + (pxx * 8 + qq);
    #pragma unroll 4
    for (int c = c0; c < c0 + 96; ++c) {
        float v = 0.f;
        #pragma unroll
        for (int n = 0; n < 9; ++n) v += bf2f(stub[n * C_ + c]) * areg[n];
        obase[(size_t)c * HW_] = v;
    }
}

extern "C" void kernel_launch(void* const* d_in, const int* in_sizes, int n_in,
                              void* d_out, int out_size, void* d_ws, size_t ws_size,
                              hipStream_t stream) {
    const float* x = (const float*)d_in[0];
    float* out = (float*)d_out;

    const size_t PIXN = (size_t)B_ * M_ * 64 * C_;      // bf16 elements
    const size_t STN  = (size_t)B_ * M_ * C_;           // fp32 elements
    const size_t need = PIXN * 2 + (STN * 11 + (size_t)B_ * M_ * 9) * 4;

    if (ws_size >= need) {
        unsigned short* pix = (unsigned short*)d_ws;
        float* stoken   = (float*)(pix + PIXN);
        float* st_part  = stoken + STN;
        float* refined  = st_part + STN * 9;
        float* normpart = refined + STN;

        k_tp  <<<B_ * HH * 24, 512, 0, stream>>>(x, pix, stoken);
        k_it0 <<<B_ * M_,      256, 0, stream>>>(pix, stoken, st_part, normpart);
        k_fold<<<B_ * M_,      256, 0, stream>>>(st_part, normpart, refined);
        k_fin <<<B_ * M_,      256, 0, stream>>>(pix, refined, out);
    } else {
        float* stoken = (float*)d_ws;
        float* raw    = stoken + STN;
        float* norm   = raw + STN;
        hipMemsetAsync(raw, 0, STN * sizeof(float), stream);
        hipMemsetAsync(norm, 0, (size_t)B_ * M_ * sizeof(float), stream);
        o_pool <<<B_ * C_ * HH, 256, 0, stream>>>(x, stoken);
        o_iter0<<<B_ * M_,      256, 0, stream>>>(x, stoken, raw, norm);
        o_final<<<B_ * M_,      256, 0, stream>>>(x, raw, norm, out);
    }
}

// Round 3
// 473.753 us; speedup vs baseline: 1.4909x; 1.4909x over previous
//
#include <hip/hip_runtime.h>
#include <cstdint>
#include <cstddef>

typedef __attribute__((ext_vector_type(8))) unsigned short us8;

#define B_ 4
#define C_ 384
#define H_ 224
#define W_ 224
#define HH 28
#define WW 28
#define HW_ (H_*W_)
#define M_ (HH*WW)
#define SCALE_ 0.05103103630798288f   // 1/sqrt(384)
#define EPS_ 1e-12f

__device__ __forceinline__ unsigned short f2bf(float f) {
    union { float f; unsigned int u; } v; v.f = f;
    unsigned int r = v.u + 0x7FFFu + ((v.u >> 16) & 1u);
    return (unsigned short)(r >> 16);
}
__device__ __forceinline__ float bf2f(unsigned short h) {
    union { unsigned int u; float f; } v; v.u = ((unsigned int)h) << 16;
    return v.f;
}

// ---------------------------------------------------------------------------
// k_tp: layout transform + pool, NO LDS. Block = (b, py, cgroup of 32 ch),
// 896 threads = (w 0..223) x (oct 0..3). Each thread owns pixel-column w,
// channels cbase..cbase+7, loops over the 8 rows of the patch-row.
//  - global reads: per (pp,j) instr, 4 runs of 16 consecutive floats (64B).
//  - pix writes: 4 adjacent lanes (oct 0..3) write 4x16B = full 64B line.
//  - pool: register psum over pp, __shfl_xor over the 8 w's of a patch.
// ---------------------------------------------------------------------------
__global__ __launch_bounds__(896) void k_tp(const float* __restrict__ x,
                                            unsigned short* __restrict__ pix,
                                            float* __restrict__ stoken) {
    int bid = blockIdx.x;
    int cg = bid % 12; int t2 = bid / 12; int py = t2 % HH; int b = t2 / HH;
    int tid = threadIdx.x;
    int w = tid >> 2;          // 0..223
    int oct = tid & 3;         // 0..3
    int pxx = w >> 3, qq = w & 7;
    int cbase = cg * 32 + oct * 8;

    const float* xb = x + ((size_t)(b * C_ + cbase) * H_ + py * 8) * W_ + w;
    unsigned short* pb = pix + (((size_t)b * M_ + py * WW + pxx) * 64) * C_ + cbase;

    float psum[8];
    #pragma unroll
    for (int j = 0; j < 8; ++j) psum[j] = 0.f;

    #pragma unroll
    for (int pp = 0; pp < 8; ++pp) {
        float v[8];
        #pragma unroll
        for (int j = 0; j < 8; ++j) v[j] = xb[(size_t)j * HW_ + (size_t)pp * W_];
        us8 o;
        #pragma unroll
        for (int j = 0; j < 8; ++j) { psum[j] += v[j]; o[j] = f2bf(v[j]); }
        *(us8*)(pb + (size_t)(pp * 8 + qq) * C_) = o;
    }

    // sum over the 8 columns of this patch (lanes stride 4 within wave)
    #pragma unroll
    for (int j = 0; j < 8; ++j) {
        float s = psum[j];
        s += __shfl_xor(s, 4);
        s += __shfl_xor(s, 8);
        s += __shfl_xor(s, 16);
        psum[j] = s;
    }
    int lane = tid & 63;
    if ((lane & 28) == 0) {    // lanes 0..3 and 32..35: one per (patch, oct)
        float* sb = stoken + ((size_t)b * M_ + py * WW + pxx) * C_ + cbase;
        #pragma unroll
        for (int j = 0; j < 8; ++j) sb[j] = psum[j] * (1.f / 64.f);
    }
}

// ---------------------------------------------------------------------------
// k_it0: iteration 0. Block per (b, patch). QK -> softmax -> st_part/normpart.
// ---------------------------------------------------------------------------
__global__ __launch_bounds__(256) void k_it0(const unsigned short* __restrict__ pix,
                                             const float* __restrict__ stoken,
                                             float* __restrict__ st_part,
                                             float* __restrict__ normpart) {
    int bid = blockIdx.x;
    int m = bid % M_, b = bid / M_;
    int py = m / WW, pxx = m - py * WW;
    int tid = threadIdx.x;
    int l = tid & 63, cgw = tid >> 6, c0 = cgw * 96;

    __shared__ float stub[9][C_];
    __shared__ float qkred[256][9];
    __shared__ float aff[64][10];

    for (int idx = tid; idx < 9 * C_; idx += 256) {
        int n = idx / C_, c = idx - n * C_;
        int yy = py + n / 3 - 1, xx = pxx + n % 3 - 1;
        float v = 0.f;
        if (yy >= 0 && yy < HH && xx >= 0 && xx < WW)
            v = stoken[((size_t)b * M_ + yy * WW + xx) * C_ + c];
        stub[n][c] = v;
    }
    __syncthreads();

    const unsigned short* prow = pix + (((size_t)b * M_ + m) * 64 + l) * C_;
    float acc[9];
    #pragma unroll
    for (int n = 0; n < 9; ++n) acc[n] = 0.f;
    for (int cc = c0; cc < c0 + 96; cc += 8) {
        us8 v = *(const us8*)(prow + cc);
        #pragma unroll
        for (int j = 0; j < 8; ++j) {
            float pv = bf2f(v[j]);
            #pragma unroll
            for (int n = 0; n < 9; ++n) acc[n] += pv * stub[n][cc + j];
        }
    }
    #pragma unroll
    for (int n = 0; n < 9; ++n) qkred[tid][n] = acc[n];
    __syncthreads();

    if (tid < 64) {
        float s[9];
        #pragma unroll
        for (int n = 0; n < 9; ++n)
            s[n] = (qkred[tid][n] + qkred[64 + tid][n] +
                    qkred[128 + tid][n] + qkred[192 + tid][n]) * SCALE_;
        float mx = s[0];
        #pragma unroll
        for (int n = 1; n < 9; ++n) mx = fmaxf(mx, s[n]);
        float den = 0.f;
        #pragma unroll
        for (int n = 0; n < 9; ++n) { float e = __expf(s[n] - mx); den += e; s[n] = e; }
        float inv = 1.f / den;
        #pragma unroll
        for (int n = 0; n < 9; ++n) aff[tid][n] = s[n] * inv;
    }
    __syncthreads();

    if (tid >= 64 && tid < 73) {
        int n = tid - 64;
        float s = 0.f;
        for (int ll = 0; ll < 64; ++ll) s += aff[ll][n];
        normpart[((size_t)b * M_ + m) * 9 + n] = s;
    }

    const unsigned short* pbase = pix + (((size_t)b * M_ + m) * 64) * C_;
    for (int c = tid; c < C_; c += 256) {
        float a2[9];
        #pragma unroll
        for (int n = 0; n < 9; ++n) a2[n] = 0.f;
        for (int ll = 0; ll < 64; ++ll) {
            float pv = bf2f(pbase[(size_t)ll * C_ + c]);
            #pragma unroll
            for (int n = 0; n < 9; ++n) a2[n] += pv * aff[ll][n];
        }
        #pragma unroll
        for (int n = 0; n < 9; ++n)
            st_part[(((size_t)b * M_ + m) * 9 + n) * C_ + c] = a2[n];
    }
}

// ---------------------------------------------------------------------------
// k_fold: gather-fold st_part into refined stokens (pre-divided by norm).
// ---------------------------------------------------------------------------
__global__ __launch_bounds__(256) void k_fold(const float* __restrict__ st_part,
                                              const float* __restrict__ normpart,
                                              float* __restrict__ refined) {
    int bid = blockIdx.x;
    int cell = bid % M_, b = bid / M_;
    int cy = cell / WW, cx = cell - cy * WW;
    int tid = threadIdx.x;

    float nsum = 0.f;
    int srcm[9]; int nsrc = 0;
    #pragma unroll
    for (int n = 0; n < 9; ++n) {
        int my = cy - (n / 3 - 1), mx = cx - (n % 3 - 1);
        if (my >= 0 && my < HH && mx >= 0 && mx < WW) {
            int mm = my * WW + mx;
            srcm[nsrc] = mm * 9 + n;
            nsum += normpart[(size_t)b * M_ * 9 + mm * 9 + n];
            ++nsrc;
        }
    }
    float inv = 1.f / (nsum + EPS_);
    for (int c = tid; c < C_; c += 256) {
        float s = 0.f;
        for (int k = 0; k < nsrc; ++k)
            s += st_part[((size_t)b * M_ * 9 + srcm[k]) * C_ + c];
        refined[((size_t)b * M_ + cell) * C_ + c] = s * inv;
    }
}

// ---------------------------------------------------------------------------
// k_aff: iteration-1 affinity only. Block per (b, patch). Writes aff with
// stride 12 floats per pixel (aligned float4 reads in k_out).
// ---------------------------------------------------------------------------
__global__ __launch_bounds__(256) void k_aff(const unsigned short* __restrict__ pix,
                                             const float* __restrict__ refined,
                                             float* __restrict__ affb) {
    int bid = blockIdx.x;
    int m = bid % M_, b = bid / M_;
    int py = m / WW, pxx = m - py * WW;
    int tid = threadIdx.x;
    int l = tid & 63, cgw = tid >> 6, c0 = cgw * 96;

    __shared__ float stub[9][C_];
    __shared__ float qkred[256][9];

    for (int idx = tid; idx < 9 * C_; idx += 256) {
        int n = idx / C_, c = idx - n * C_;
        int yy = py + n / 3 - 1, xx = pxx + n % 3 - 1;
        float v = 0.f;
        if (yy >= 0 && yy < HH && xx >= 0 && xx < WW)
            v = refined[((size_t)b * M_ + yy * WW + xx) * C_ + c];
        stub[n][c] = v;
    }
    __syncthreads();

    const unsigned short* prow = pix + (((size_t)b * M_ + m) * 64 + l) * C_;
    float acc[9];
    #pragma unroll
    for (int n = 0; n < 9; ++n) acc[n] = 0.f;
    for (int cc = c0; cc < c0 + 96; cc += 8) {
        us8 v = *(const us8*)(prow + cc);
        #pragma unroll
        for (int j = 0; j < 8; ++j) {
            float pv = bf2f(v[j]);
            #pragma unroll
            for (int n = 0; n < 9; ++n) acc[n] += pv * stub[n][cc + j];
        }
    }
    #pragma unroll
    for (int n = 0; n < 9; ++n) qkred[tid][n] = acc[n];
    __syncthreads();

    if (tid < 64) {
        float s[9];
        #pragma unroll
        for (int n = 0; n < 9; ++n)
            s[n] = (qkred[tid][n] + qkred[64 + tid][n] +
                    qkred[128 + tid][n] + qkred[192 + tid][n]) * SCALE_;
        float mx = s[0];
        #pragma unroll
        for (int n = 1; n < 9; ++n) mx = fmaxf(mx, s[n]);
        float den = 0.f;
        #pragma unroll
        for (int n = 0; n < 9; ++n) { float e = __expf(s[n] - mx); den += e; s[n] = e; }
        float inv = 1.f / den;
        float* ap = affb + (((size_t)b * M_ + m) * 64 + tid) * 12;
        #pragma unroll
        for (int n = 0; n < 9; ++n) ap[n] = s[n] * inv;
    }
}

// ---------------------------------------------------------------------------
// k_out: broadcast. Block = (b, py, cgroup of 32 ch), 896 threads =
// (ci 0..3) x (w 0..223). Full-line out stores (consecutive w per wave).
// stub LDS padded [3][30][33]: bank = ~(xx + c) mod 32 -> conflict-free.
// ---------------------------------------------------------------------------
__global__ __launch_bounds__(896) void k_out(const float* __restrict__ refined,
                                             const float* __restrict__ affb,
                                             float* __restrict__ out) {
    int bid = blockIdx.x;
    int cg = bid % 12; int t2 = bid / 12; int py = t2 % HH; int b = t2 / HH;
    int c0 = cg * 32;
    int tid = threadIdx.x;
    int w = tid % 224, ci = tid / 224;
    int pxx = w >> 3, qq = w & 7;

    __shared__ float stub[3][30][33];
    for (int idx = tid; idx < 3 * 30 * 32; idx += 896) {
        int r = idx / 960; int rem = idx - r * 960;
        int xxp = rem >> 5; int cc = rem & 31;
        int yy = py + r - 1, xx = xxp - 1;
        float v = 0.f;
        if (yy >= 0 && yy < HH && xx >= 0 && xx < WW)
            v = refined[((size_t)b * M_ + yy * WW + xx) * C_ + c0 + cc];
        stub[r][xxp][cc] = v;
    }
    __syncthreads();

    const float* ab = affb + (((size_t)b * M_ + py * WW + pxx) * 64) * 12;
    float* ob = out + ((size_t)(b * C_) * H_ + py * 8) * W_ + w;

    for (int pp = 0; pp < 8; ++pp) {
        int l = pp * 8 + qq;
        const float* ap = ab + l * 12;
        float4 a0 = *(const float4*)ap;
        float4 a4 = *(const float4*)(ap + 4);
        float a8 = ap[8];
        float an[9] = {a0.x, a0.y, a0.z, a0.w, a4.x, a4.y, a4.z, a4.w, a8};
        #pragma unroll
        for (int k = 0; k < 8; ++k) {
            int cc = ci + k * 4;
            float s = 0.f;
            #pragma unroll
            for (int n = 0; n < 9; ++n)
                s += stub[n / 3][pxx + (n % 3)][cc] * an[n];
            ob[(size_t)(c0 + cc) * HW_ + (size_t)pp * W_] = s;
        }
    }
}

// ===========================================================================
// Fallback path (round-1 kernels) if ws_size is too small.
// ===========================================================================
__global__ __launch_bounds__(256) void o_pool(const float* __restrict__ x,
                                              float* __restrict__ stoken) {
    int bid = blockIdx.x;
    int yy = bid % HH;
    int t  = bid / HH;
    int c  = t % C_;
    int b  = t / C_;
    __shared__ float colsum[W_];
    int q = threadIdx.x;
    if (q < W_) {
        const float* base = x + ((size_t)(b * C_ + c) * H_ + yy * 8) * W_ + q;
        float s = 0.f;
        #pragma unroll
        for (int p = 0; p < 8; ++p) s += base[(size_t)p * W_];
        colsum[q] = s;
    }
    __syncthreads();
    if (q < WW) {
        float s = 0.f;
        #pragma unroll
        for (int j = 0; j < 8; ++j) s += colsum[q * 8 + j];
        stoken[(((size_t)b * HH + yy) * WW + q) * C_ + c] = s * (1.f / 64.f);
    }
}

__global__ __launch_bounds__(256) void o_iter0(const float* __restrict__ x,
                                               const float* __restrict__ stoken,
                                               float* __restrict__ raw,
                                               float* __restrict__ norm) {
    int bid = blockIdx.x;
    int m = bid % M_;
    int b = bid / M_;
    int py = m / WW, pxx = m % WW;
    int tid = threadIdx.x;
    int w = tid >> 6, l = tid & 63;
    int pp = l >> 3, qq = l & 7;

    __shared__ unsigned short pixs[C_][66];
    __shared__ float sbuf[2304];
    __shared__ float aff[64][10];
    unsigned short* stub = (unsigned short*)sbuf;

    for (int idx = tid; idx < 9 * C_; idx += 256) {
        int n = idx / C_, c = idx - n * C_;
        int yy = py + n / 3 - 1, xx = pxx + n % 3 - 1;
        float v = 0.f;
        if (yy >= 0 && yy < HH && xx >= 0 && xx < WW)
            v = stoken[(((size_t)b * HH + yy) * WW + xx) * C_ + c];
        stub[idx] = f2bf(v);
    }
    __syncthreads();

    const float* pxbase = x + (size_t)b * C_ * HW_ + (size_t)(py * 8 + pp) * W_ + (pxx * 8 + qq);
    float acc[9];
    #pragma unroll
    for (int n = 0; n < 9; ++n) acc[n] = 0.f;
    int c0 = w * 96;
    #pragma unroll 4
    for (int c = c0; c < c0 + 96; ++c) {
        float pv = pxbase[(size_t)c * HW_];
        pixs[c][l] = f2bf(pv);
        #pragma unroll
        for (int n = 0; n < 9; ++n) acc[n] += pv * bf2f(stub[n * C_ + c]);
    }
    __syncthreads();
    float* qkred = sbuf;
    #pragma unroll
    for (int n = 0; n < 9; ++n) qkred[tid * 9 + n] = acc[n];
    __syncthreads();

    if (tid < 64) {
        float s[9];
        #pragma unroll
        for (int n = 0; n < 9; ++n)
            s[n] = (qkred[(0 * 64 + tid) * 9 + n] + qkred[(1 * 64 + tid) * 9 + n] +
                    qkred[(2 * 64 + tid) * 9 + n] + qkred[(3 * 64 + tid) * 9 + n]) * SCALE_;
        float mx = s[0];
        #pragma unroll
        for (int n = 1; n < 9; ++n) mx = fmaxf(mx, s[n]);
        float den = 0.f;
        #pragma unroll
        for (int n = 0; n < 9; ++n) { float e = __expf(s[n] - mx); den += e; s[n] = e; }
        float inv = 1.f / den;
        #pragma unroll
        for (int n = 0; n < 9; ++n) aff[tid][n] = s[n] * inv;
    }
    __syncthreads();

    if (tid < 9) {
        float s = 0.f;
        for (int ll = 0; ll < 64; ++ll) s += aff[ll][tid];
        int ty = py + tid / 3 - 1, tx = pxx + tid % 3 - 1;
        if (ty >= 0 && ty < HH && tx >= 0 && tx < WW)
            atomicAdd(&norm[((size_t)b * HH + ty) * WW + tx], s);
    }

    for (int c = tid; c < C_; c += 256) {
        float a2[9];
        #pragma unroll
        for (int n = 0; n < 9; ++n) a2[n] = 0.f;
        for (int ll = 0; ll < 64; ++ll) {
            float pv = bf2f(pixs[c][ll]);
            #pragma unroll
            for (int n = 0; n < 9; ++n) a2[n] += pv * aff[ll][n];
        }
        #pragma unroll
        for (int n = 0; n < 9; ++n) {
            int ty = py + n / 3 - 1, tx = pxx + n % 3 - 1;
            if (ty >= 0 && ty < HH && tx >= 0 && tx < WW)
                atomicAdd(&raw[(((size_t)b * HH + ty) * WW + tx) * C_ + c], a2[n]);
        }
    }
}

__global__ __launch_bounds__(256) void o_final(const float* __restrict__ x,
                                               const float* __restrict__ raw,
                                               const float* __restrict__ norm,
                                               float* __restrict__ out) {
    int bid = blockIdx.x;
    int m = bid % M_;
    int b = bid / M_;
    int py = m / WW, pxx = m % WW;
    int tid = threadIdx.x;
    int w = tid >> 6, l = tid & 63;
    int pp = l >> 3, qq = l & 7;

    __shared__ unsigned short stub[9 * C_];
    __shared__ float qkred[4 * 64 * 9];
    __shared__ float aff[64][10];

    for (int idx = tid; idx < 9 * C_; idx += 256) {
        int n = idx / C_, c = idx - n * C_;
        int yy = py + n / 3 - 1, xx = pxx + n % 3 - 1;
        float v = 0.f;
        if (yy >= 0 && yy < HH && xx >= 0 && xx < WW) {
            size_t cell = ((size_t)b * HH + yy) * WW + xx;
            v = raw[cell * C_ + c] / (norm[cell] + EPS_);
        }
        stub[idx] = f2bf(v);
    }
    __syncthreads();

    const float* pxbase = x + (size_t)b * C_ * HW_ + (size_t)(py * 8 + pp) * W_ + (pxx * 8 + qq);
    float acc[9];
    #pragma unroll
    for (int n = 0; n < 9; ++n) acc[n] = 0.f;
    int c0 = w * 96;
    #pragma unroll 4
    for (int c = c0; c < c0 + 96; ++c) {
        float pv = pxbase[(size_t)c * HW_];
        #pragma unroll
        for (int n = 0; n < 9; ++n) acc[n] += pv * bf2f(stub[n * C_ + c]);
    }
    #pragma unroll
    for (int n = 0; n < 9; ++n) qkred[tid * 9 + n] = acc[n];
    __syncthreads();

    if (tid < 64) {
        float s[9];
        #pragma unroll
        for (int n = 0; n < 9; ++n)
            s[n] = (qkred[(0 * 64 + tid) * 9 + n] + qkred[(1 * 64 + tid) * 9 + n] +
                    qkred[(2 * 64 + tid) * 9 + n] + qkred[(3 * 64 + tid) * 9 + n]) * SCALE_;
        float mx = s[0];
        #pragma unroll
        for (int n = 1; n < 9; ++n) mx = fmaxf(mx, s[n]);
        float den = 0.f;
        #pragma unroll
        for (int n = 0; n < 9; ++n) { float e = __expf(s[n] - mx); den += e; s[n] = e; }
        float inv = 1.f / den;
        #pragma unroll
        for (int n = 0; n < 9; ++n) aff[tid][n] = s[n] * inv;
    }
    __syncthreads();

    float areg[9];
    #pragma unroll
    for (int n = 0; n < 9; ++n) areg[n] = aff[l][n];
    float* obase = out + (size_t)b * C_ * HW_ + (size_t)(py * 8 + pp) * W_ + (pxx * 8 + qq);
    #pragma unroll 4
    for (int c = c0; c < c0 + 96; ++c) {
        float v = 0.f;
        #pragma unroll
        for (int n = 0; n < 9; ++n) v += bf2f(stub[n * C_ + c]) * areg[n];
        obase[(size_t)c * HW_] = v;
    }
}

extern "C" void kernel_launch(void* const* d_in, const int* in_sizes, int n_in,
                              void* d_out, int out_size, void* d_ws, size_t ws_size,
                              hipStream_t stream) {
    const float* x = (const float*)d_in[0];
    float* out = (float*)d_out;

    const size_t PIXN = (size_t)B_ * M_ * 64 * C_;      // bf16 elements
    const size_t STN  = (size_t)B_ * M_ * C_;           // fp32 elements
    const size_t AFFN = (size_t)B_ * M_ * 64 * 12;      // fp32 elements
    const size_t need = PIXN * 2 + (STN * 11 + (size_t)B_ * M_ * 9 + AFFN) * 4;

    if (ws_size >= need) {
        unsigned short* pix = (unsigned short*)d_ws;
        float* stoken   = (float*)(pix + PIXN);
        float* st_part  = stoken + STN;
        float* refined  = st_part + STN * 9;
        float* normpart = refined + STN;
        float* affb     = normpart + (size_t)B_ * M_ * 9;

        k_tp  <<<B_ * HH * 12, 896, 0, stream>>>(x, pix, stoken);
        k_it0 <<<B_ * M_,      256, 0, stream>>>(pix, stoken, st_part, normpart);
        k_fold<<<B_ * M_,      256, 0, stream>>>(st_part, normpart, refined);
        k_aff <<<B_ * M_,      256, 0, stream>>>(pix, refined, affb);
        k_out <<<B_ * HH * 12, 896, 0, stream>>>(refined, affb, out);
    } else {
        float* stoken = (float*)d_ws;
        float* raw    = stoken + STN;
        float* norm   = raw + STN;
        hipMemsetAsync(raw, 0, STN * sizeof(float), stream);
        hipMemsetAsync(norm, 0, (size_t)B_ * M_ * sizeof(float), stream);
        o_pool <<<B_ * C_ * HH, 256, 0, stream>>>(x, stoken);
        o_iter0<<<B_ * M_,      256, 0, stream>>>(x, stoken, raw, norm);
        o_final<<<B_ * M_,      256, 0, stream>>>(x, raw, norm, out);
    }
}

// Round 4
// 462.186 us; speedup vs baseline: 1.5282x; 1.0250x over previous
//
#include <hip/hip_runtime.h>
#include <cstdint>
#include <cstddef>

typedef __attribute__((ext_vector_type(8))) unsigned short us8;
typedef __attribute__((ext_vector_type(8))) short short8;
typedef __attribute__((ext_vector_type(4))) float f4v;

#define B_ 4
#define C_ 384
#define H_ 224
#define W_ 224
#define HH 28
#define WW 28
#define HW_ (H_*W_)
#define M_ (HH*WW)
#define SCALE_ 0.05103103630798288f   // 1/sqrt(384)
#define EPS_ 1e-12f

__device__ __forceinline__ unsigned short f2bf(float f) {
    union { float f; unsigned int u; } v; v.f = f;
    unsigned int r = v.u + 0x7FFFu + ((v.u >> 16) & 1u);
    return (unsigned short)(r >> 16);
}
__device__ __forceinline__ float bf2f(unsigned short h) {
    union { unsigned int u; float f; } v; v.u = ((unsigned int)h) << 16;
    return v.f;
}

// ---------------------------------------------------------------------------
// k_tp: layout transform + pool, no LDS. Block = (b, py, cgroup of 32 ch),
// 896 threads = (w 0..223) x (oct 0..3). j-outer register staging: 8 rows of
// 8 channel planes into v[pp][j], then pix us8 stores (full 64B lines across
// oct lanes) and pooled stoken in BF16 (us8) for MFMA B-fragments.
// ---------------------------------------------------------------------------
__global__ __launch_bounds__(896) void k_tp(const float* __restrict__ x,
                                            unsigned short* __restrict__ pix,
                                            unsigned short* __restrict__ stokenBF) {
    int bid = blockIdx.x;
    int cg = bid % 12; int t2 = bid / 12; int py = t2 % HH; int b = t2 / HH;
    int tid = threadIdx.x;
    int w = tid >> 2;          // 0..223
    int oct = tid & 3;         // 0..3
    int pxx = w >> 3, qq = w & 7;
    int cbase = cg * 32 + oct * 8;

    const float* xb = x + ((size_t)(b * C_ + cbase) * H_ + py * 8) * W_ + w;
    unsigned short* pb = pix + (((size_t)b * M_ + py * WW + pxx) * 64) * C_ + cbase;

    float v[8][8];   // [pp][j]
    #pragma unroll
    for (int j = 0; j < 8; ++j)
        #pragma unroll
        for (int pp = 0; pp < 8; ++pp)
            v[pp][j] = xb[(size_t)j * HW_ + (size_t)pp * W_];

    #pragma unroll
    for (int pp = 0; pp < 8; ++pp) {
        us8 o;
        #pragma unroll
        for (int j = 0; j < 8; ++j) o[j] = f2bf(v[pp][j]);
        *(us8*)(pb + (size_t)(pp * 8 + qq) * C_) = o;
    }

    float psum[8];
    #pragma unroll
    for (int j = 0; j < 8; ++j) {
        float s = 0.f;
        #pragma unroll
        for (int pp = 0; pp < 8; ++pp) s += v[pp][j];
        s += __shfl_xor(s, 4);
        s += __shfl_xor(s, 8);
        s += __shfl_xor(s, 16);
        psum[j] = s;
    }
    int lane = tid & 63;
    if ((lane & 28) == 0) {    // one lane per (patch, oct)
        us8 o;
        #pragma unroll
        for (int j = 0; j < 8; ++j) o[j] = f2bf(psum[j] * (1.f / 64.f));
        *(us8*)(stokenBF + ((size_t)b * M_ + py * WW + pxx) * C_ + cbase) = o;
    }
}

// ---------------------------------------------------------------------------
// QK via MFMA: per wave, one patch, M-tile mt (16 pixels), K=384 (12 k-tiles).
// A-frag: us8 direct from pix[l][c] (row=lane&15, k=(lane>>4)*8+j).
// B-frag: us8 direct from bf16 token buffer at the n-th neighbor cell
// (col n=lane&15; OOB or n>=9 -> zeros, matching reference zero-pad logits).
// D-frag: col=lane&15, row=(lane>>4)*4+reg (m89-verified mapping).
// ---------------------------------------------------------------------------
__device__ __forceinline__ f4v qk_wave(const unsigned short* __restrict__ pixP,
                                       const unsigned short* __restrict__ bfbase,
                                       int b, int py, int pxx, int mt) {
    int lane = threadIdx.x & 63;
    int n = lane & 15, g = lane >> 4;
    int yy = py + n / 3 - 1, xx = pxx + n % 3 - 1;
    bool valid = (n < 9) && yy >= 0 && yy < HH && xx >= 0 && xx < WW;
    size_t cell = valid ? ((size_t)b * M_ + (size_t)yy * WW + xx) : 0;
    const unsigned short* bp = bfbase + cell * C_ + g * 8;
    const unsigned short* ap = pixP + (size_t)(mt * 16 + n) * C_ + g * 8;
    const short8 zz = {0, 0, 0, 0, 0, 0, 0, 0};
    f4v acc = {0.f, 0.f, 0.f, 0.f};
    #pragma unroll
    for (int kt = 0; kt < 12; ++kt) {
        short8 a = *(const short8*)(ap + kt * 32);
        short8 bv = *(const short8*)(bp + kt * 32);
        if (!valid) bv = zz;
        acc = __builtin_amdgcn_mfma_f32_16x16x32_bf16(a, bv, acc, 0, 0, 0);
    }
    return acc;
}

// Softmax on the D-fragment: rows are per-reg, cols are lanes within the
// 16-lane group. Butterfly max/sum over cols; cols 9..15 masked to -inf.
__device__ __forceinline__ void softmax_wave(const f4v s, float aout[4]) {
    int lane = threadIdx.x & 63;
    bool coln = (lane & 15) < 9;
    float v[4], e[4], mx[4], su[4];
    #pragma unroll
    for (int r = 0; r < 4; ++r) v[r] = coln ? s[r] * SCALE_ : -3e38f;
    #pragma unroll
    for (int r = 0; r < 4; ++r) mx[r] = v[r];
    #pragma unroll
    for (int d = 1; d < 16; d <<= 1)
        #pragma unroll
        for (int r = 0; r < 4; ++r) mx[r] = fmaxf(mx[r], __shfl_xor(mx[r], d));
    #pragma unroll
    for (int r = 0; r < 4; ++r) e[r] = coln ? __expf(v[r] - mx[r]) : 0.f;
    #pragma unroll
    for (int r = 0; r < 4; ++r) su[r] = e[r];
    #pragma unroll
    for (int d = 1; d < 16; d <<= 1)
        #pragma unroll
        for (int r = 0; r < 4; ++r) su[r] += __shfl_xor(su[r], d);
    #pragma unroll
    for (int r = 0; r < 4; ++r) aout[r] = e[r] / su[r];
}

// ---------------------------------------------------------------------------
// k_it0: iteration 0. Block per (b,patch), 4 waves = 4 M-tiles.
// MFMA QK -> softmax -> aff32 LDS (fp32) + normpart; then VALU phase2:
// st_part[n][c] = sum_l pix[l][c]*aff[l][n].
// ---------------------------------------------------------------------------
__global__ __launch_bounds__(256) void k_it0(const unsigned short* __restrict__ pix,
                                             const unsigned short* __restrict__ stokenBF,
                                             float* __restrict__ st_part,
                                             float* __restrict__ normpart) {
    int bid = blockIdx.x;
    int m = bid % M_, b = bid / M_;
    int py = m / WW, pxx = m - py * WW;
    int tid = threadIdx.x;
    int wid = tid >> 6, lane = tid & 63;
    int n = lane & 15, g = lane >> 4;

    __shared__ float aff32[64][12];
    __shared__ float npart[4][16];

    const unsigned short* pixP = pix + (size_t)bid * 64 * C_;
    f4v s = qk_wave(pixP, stokenBF, b, py, pxx, wid);
    float a[4];
    softmax_wave(s, a);

    if (n < 9) {
        #pragma unroll
        for (int r = 0; r < 4; ++r) aff32[wid * 16 + g * 4 + r][n] = a[r];
    }
    float p = a[0] + a[1] + a[2] + a[3];
    p += __shfl_xor(p, 16);
    p += __shfl_xor(p, 32);
    if (lane < 9) npart[wid][lane] = p;
    __syncthreads();

    if (tid < 9)
        normpart[(size_t)bid * 9 + tid] =
            npart[0][tid] + npart[1][tid] + npart[2][tid] + npart[3][tid];

    // phase 2: per-channel accumulate over 64 pixels (aff broadcast from LDS)
    for (int c = tid; c < C_; c += 256) {
        float acc9[9];
        #pragma unroll
        for (int k = 0; k < 9; ++k) acc9[k] = 0.f;
        const unsigned short* pb = pixP + c;
        for (int l = 0; l < 64; ++l) {
            float pv = bf2f(pb[(size_t)l * C_]);
            const float4* arow = (const float4*)aff32[l];
            float4 a0 = arow[0], a1 = arow[1];
            float a8 = aff32[l][8];
            acc9[0] += pv * a0.x; acc9[1] += pv * a0.y;
            acc9[2] += pv * a0.z; acc9[3] += pv * a0.w;
            acc9[4] += pv * a1.x; acc9[5] += pv * a1.y;
            acc9[6] += pv * a1.z; acc9[7] += pv * a1.w;
            acc9[8] += pv * a8;
        }
        #pragma unroll
        for (int k = 0; k < 9; ++k)
            st_part[((size_t)bid * 9 + k) * C_ + c] = acc9[k];
    }
}

// ---------------------------------------------------------------------------
// k_fold: gather-fold st_part into refined stokens (pre-divided by norm).
// Emits fp32 (for k_out) and bf16 (for k_aff B-fragments).
// ---------------------------------------------------------------------------
__global__ __launch_bounds__(256) void k_fold(const float* __restrict__ st_part,
                                              const float* __restrict__ normpart,
                                              float* __restrict__ refined,
                                              unsigned short* __restrict__ refinedBF) {
    int bid = blockIdx.x;
    int cell = bid % M_, b = bid / M_;
    int cy = cell / WW, cx = cell - cy * WW;
    int tid = threadIdx.x;

    float nsum = 0.f;
    int srcm[9]; int nsrc = 0;
    #pragma unroll
    for (int nn = 0; nn < 9; ++nn) {
        int my = cy - (nn / 3 - 1), mx = cx - (nn % 3 - 1);
        if (my >= 0 && my < HH && mx >= 0 && mx < WW) {
            int mm = my * WW + mx;
            srcm[nsrc] = mm * 9 + nn;
            nsum += normpart[(size_t)b * M_ * 9 + mm * 9 + nn];
            ++nsrc;
        }
    }
    float inv = 1.f / (nsum + EPS_);
    for (int c = tid; c < C_; c += 256) {
        float s = 0.f;
        for (int k = 0; k < nsrc; ++k)
            s += st_part[((size_t)b * M_ * 9 + srcm[k]) * C_ + c];
        float r = s * inv;
        refined[((size_t)b * M_ + cell) * C_ + c] = r;
        refinedBF[((size_t)b * M_ + cell) * C_ + c] = f2bf(r);
    }
}

// ---------------------------------------------------------------------------
// k_aff: iteration-1 affinity. Block per (b,patch), wave = M-tile.
// MFMA QK against refinedBF -> softmax -> affb (fp32, stride 12).
// ---------------------------------------------------------------------------
__global__ __launch_bounds__(256) void k_aff(const unsigned short* __restrict__ pix,
                                             const unsigned short* __restrict__ refinedBF,
                                             float* __restrict__ affb) {
    int bid = blockIdx.x;
    int m = bid % M_, b = bid / M_;
    int py = m / WW, pxx = m - py * WW;
    int tid = threadIdx.x;
    int wid = tid >> 6, lane = tid & 63;
    int n = lane & 15, g = lane >> 4;

    const unsigned short* pixP = pix + (size_t)bid * 64 * C_;
    f4v s = qk_wave(pixP, refinedBF, b, py, pxx, wid);
    float a[4];
    softmax_wave(s, a);

    if (n < 9) {
        float* ap = affb + ((size_t)bid * 64 + wid * 16 + g * 4) * 12 + n;
        #pragma unroll
        for (int r = 0; r < 4; ++r) ap[r * 12] = a[r];
    }
}

// ---------------------------------------------------------------------------
// k_out: broadcast. Block = (b, py, cgroup of 32 ch), 896 threads =
// (ci 0..3) x (w 0..223). Stub hoisted to registers (2 half-K passes of 36);
// full-line out stores.
// ---------------------------------------------------------------------------
__global__ __launch_bounds__(896) void k_out(const float* __restrict__ refined,
                                             const float* __restrict__ affb,
                                             float* __restrict__ out) {
    int bid = blockIdx.x;
    int cg = bid % 12; int t2 = bid / 12; int py = t2 % HH; int b = t2 / HH;
    int c0 = cg * 32;
    int tid = threadIdx.x;
    int w = tid % 224, ci = tid / 224;
    int pxx = w >> 3, qq = w & 7;

    __shared__ float stub[3][30][33];
    for (int idx = tid; idx < 3 * 30 * 32; idx += 896) {
        int r = idx / 960; int rem = idx - r * 960;
        int xxp = rem >> 5; int cc = rem & 31;
        int yy = py + r - 1, xx = xxp - 1;
        float v = 0.f;
        if (yy >= 0 && yy < HH && xx >= 0 && xx < WW)
            v = refined[((size_t)b * M_ + yy * WW + xx) * C_ + c0 + cc];
        stub[r][xxp][cc] = v;
    }
    __syncthreads();

    const float* ab = affb + ((size_t)b * M_ + py * WW + pxx) * 64 * 12;
    float* ob = out + ((size_t)(b * C_) * H_ + py * 8) * W_ + w;

    #pragma unroll
    for (int kh = 0; kh < 2; ++kh) {
        float sreg[9][4];
        #pragma unroll
        for (int nn = 0; nn < 9; ++nn)
            #pragma unroll
            for (int k = 0; k < 4; ++k)
                sreg[nn][k] = stub[nn / 3][pxx + nn % 3][ci + (kh * 4 + k) * 4];
        for (int pp = 0; pp < 8; ++pp) {
            const float* ap = ab + (pp * 8 + qq) * 12;
            float4 a0 = *(const float4*)ap;
            float4 a4 = *(const float4*)(ap + 4);
            float a8 = ap[8];
            float an[9] = {a0.x, a0.y, a0.z, a0.w, a4.x, a4.y, a4.z, a4.w, a8};
            #pragma unroll
            for (int k = 0; k < 4; ++k) {
                float s = 0.f;
                #pragma unroll
                for (int nn = 0; nn < 9; ++nn) s += sreg[nn][k] * an[nn];
                ob[(size_t)(c0 + ci + (kh * 4 + k) * 4) * HW_ + (size_t)pp * W_] = s;
            }
        }
    }
}

// ===========================================================================
// Fallback path (round-1 kernels) if ws_size is too small.
// ===========================================================================
__global__ __launch_bounds__(256) void o_pool(const float* __restrict__ x,
                                              float* __restrict__ stoken) {
    int bid = blockIdx.x;
    int yy = bid % HH;
    int t  = bid / HH;
    int c  = t % C_;
    int b  = t / C_;
    __shared__ float colsum[W_];
    int q = threadIdx.x;
    if (q < W_) {
        const float* base = x + ((size_t)(b * C_ + c) * H_ + yy * 8) * W_ + q;
        float s = 0.f;
        #pragma unroll
        for (int p = 0; p < 8; ++p) s += base[(size_t)p * W_];
        colsum[q] = s;
    }
    __syncthreads();
    if (q < WW) {
        float s = 0.f;
        #pragma unroll
        for (int j = 0; j < 8; ++j) s += colsum[q * 8 + j];
        stoken[(((size_t)b * HH + yy) * WW + q) * C_ + c] = s * (1.f / 64.f);
    }
}

__global__ __launch_bounds__(256) void o_iter0(const float* __restrict__ x,
                                               const float* __restrict__ stoken,
                                               float* __restrict__ raw,
                                               float* __restrict__ norm) {
    int bid = blockIdx.x;
    int m = bid % M_;
    int b = bid / M_;
    int py = m / WW, pxx = m % WW;
    int tid = threadIdx.x;
    int w = tid >> 6, l = tid & 63;
    int pp = l >> 3, qq = l & 7;

    __shared__ unsigned short pixs[C_][66];
    __shared__ float sbuf[2304];
    __shared__ float aff[64][10];
    unsigned short* stub = (unsigned short*)sbuf;

    for (int idx = tid; idx < 9 * C_; idx += 256) {
        int nn = idx / C_, c = idx - nn * C_;
        int yy = py + nn / 3 - 1, xx = pxx + nn % 3 - 1;
        float v = 0.f;
        if (yy >= 0 && yy < HH && xx >= 0 && xx < WW)
            v = stoken[(((size_t)b * HH + yy) * WW + xx) * C_ + c];
        stub[idx] = f2bf(v);
    }
    __syncthreads();

    const float* pxbase = x + (size_t)b * C_ * HW_ + (size_t)(py * 8 + pp) * W_ + (pxx * 8 + qq);
    float acc[9];
    #pragma unroll
    for (int nn = 0; nn < 9; ++nn) acc[nn] = 0.f;
    int c0 = w * 96;
    #pragma unroll 4
    for (int c = c0; c < c0 + 96; ++c) {
        float pv = pxbase[(size_t)c * HW_];
        pixs[c][l] = f2bf(pv);
        #pragma unroll
        for (int nn = 0; nn < 9; ++nn) acc[nn] += pv * bf2f(stub[nn * C_ + c]);
    }
    __syncthreads();
    float* qkred = sbuf;
    #pragma unroll
    for (int nn = 0; nn < 9; ++nn) qkred[tid * 9 + nn] = acc[nn];
    __syncthreads();

    if (tid < 64) {
        float s[9];
        #pragma unroll
        for (int nn = 0; nn < 9; ++nn)
            s[nn] = (qkred[(0 * 64 + tid) * 9 + nn] + qkred[(1 * 64 + tid) * 9 + nn] +
                     qkred[(2 * 64 + tid) * 9 + nn] + qkred[(3 * 64 + tid) * 9 + nn]) * SCALE_;
        float mx = s[0];
        #pragma unroll
        for (int nn = 1; nn < 9; ++nn) mx = fmaxf(mx, s[nn]);
        float den = 0.f;
        #pragma unroll
        for (int nn = 0; nn < 9; ++nn) { float e = __expf(s[nn] - mx); den += e; s[nn] = e; }
        float inv = 1.f / den;
        #pragma unroll
        for (int nn = 0; nn < 9; ++nn) aff[tid][nn] = s[nn] * inv;
    }
    __syncthreads();

    if (tid < 9) {
        float s = 0.f;
        for (int ll = 0; ll < 64; ++ll) s += aff[ll][tid];
        int ty = py + tid / 3 - 1, tx = pxx + tid % 3 - 1;
        if (ty >= 0 && ty < HH && tx >= 0 && tx < WW)
            atomicAdd(&norm[((size_t)b * HH + ty) * WW + tx], s);
    }

    for (int c = tid; c < C_; c += 256) {
        float a2[9];
        #pragma unroll
        for (int nn = 0; nn < 9; ++nn) a2[nn] = 0.f;
        for (int ll = 0; ll < 64; ++ll) {
            float pv = bf2f(pixs[c][ll]);
            #pragma unroll
            for (int nn = 0; nn < 9; ++nn) a2[nn] += pv * aff[ll][nn];
        }
        #pragma unroll
        for (int nn = 0; nn < 9; ++nn) {
            int ty = py + nn / 3 - 1, tx = pxx + nn % 3 - 1;
            if (ty >= 0 && ty < HH && tx >= 0 && tx < WW)
                atomicAdd(&raw[(((size_t)b * HH + ty) * WW + tx) * C_ + c], a2[nn]);
        }
    }
}

__global__ __launch_bounds__(256) void o_final(const float* __restrict__ x,
                                               const float* __restrict__ raw,
                                               const float* __restrict__ norm,
                                               float* __restrict__ out) {
    int bid = blockIdx.x;
    int m = bid % M_;
    int b = bid / M_;
    int py = m / WW, pxx = m % WW;
    int tid = threadIdx.x;
    int w = tid >> 6, l = tid & 63;
    int pp = l >> 3, qq = l & 7;

    __shared__ unsigned short stub[9 * C_];
    __shared__ float qkred[4 * 64 * 9];
    __shared__ float aff[64][10];

    for (int idx = tid; idx < 9 * C_; idx += 256) {
        int nn = idx / C_, c = idx - nn * C_;
        int yy = py + nn / 3 - 1, xx = pxx + nn % 3 - 1;
        float v = 0.f;
        if (yy >= 0 && yy < HH && xx >= 0 && xx < WW) {
            size_t cell = ((size_t)b * HH + yy) * WW + xx;
            v = raw[cell * C_ + c] / (norm[cell] + EPS_);
        }
        stub[idx] = f2bf(v);
    }
    __syncthreads();

    const float* pxbase = x + (size_t)b * C_ * HW_ + (size_t)(py * 8 + pp) * W_ + (pxx * 8 + qq);
    float acc[9];
    #pragma unroll
    for (int nn = 0; nn < 9; ++nn) acc[nn] = 0.f;
    int c0 = w * 96;
    #pragma unroll 4
    for (int c = c0; c < c0 + 96; ++c) {
        float pv = pxbase[(size_t)c * HW_];
        #pragma unroll
        for (int nn = 0; nn < 9; ++nn) acc[nn] += pv * bf2f(stub[nn * C_ + c]);
    }
    #pragma unroll
    for (int nn = 0; nn < 9; ++nn) qkred[tid * 9 + nn] = acc[nn];
    __syncthreads();

    if (tid < 64) {
        float s[9];
        #pragma unroll
        for (int nn = 0; nn < 9; ++nn)
            s[nn] = (qkred[(0 * 64 + tid) * 9 + nn] + qkred[(1 * 64 + tid) * 9 + nn] +
                     qkred[(2 * 64 + tid) * 9 + nn] + qkred[(3 * 64 + tid) * 9 + nn]) * SCALE_;
        float mx = s[0];
        #pragma unroll
        for (int nn = 1; nn < 9; ++nn) mx = fmaxf(mx, s[nn]);
        float den = 0.f;
        #pragma unroll
        for (int nn = 0; nn < 9; ++nn) { float e = __expf(s[nn] - mx); den += e; s[nn] = e; }
        float inv = 1.f / den;
        #pragma unroll
        for (int nn = 0; nn < 9; ++nn) aff[tid][nn] = s[nn] * inv;
    }
    __syncthreads();

    float areg[9];
    #pragma unroll
    for (int nn = 0; nn < 9; ++nn) areg[nn] = aff[l][nn];
    float* obase = out + (size_t)b * C_ * HW_ + (size_t)(py * 8 + pp) * W_ + (pxx * 8 + qq);
    #pragma unroll 4
    for (int c = c0; c < c0 + 96; ++c) {
        float v = 0.f;
        #pragma unroll
        for (int nn = 0; nn < 9; ++nn) v += bf2f(stub[nn * C_ + c]) * areg[nn];
        obase[(size_t)c * HW_] = v;
    }
}

extern "C" void kernel_launch(void* const* d_in, const int* in_sizes, int n_in,
                              void* d_out, int out_size, void* d_ws, size_t ws_size,
                              hipStream_t stream) {
    const float* x = (const float*)d_in[0];
    float* out = (float*)d_out;

    const size_t PIXN = (size_t)B_ * M_ * 64 * C_;      // bf16 elements
    const size_t STN  = (size_t)B_ * M_ * C_;           // elements per stoken set
    const size_t AFFN = (size_t)B_ * M_ * 64 * 12;      // fp32 elements
    const size_t need = PIXN * 2                         // pix bf16
                      + STN * 2                          // stokenBF
                      + STN * 2                          // refinedBF
                      + (STN * 10                        // st_part(9) + refined(1) fp32
                         + (size_t)B_ * M_ * 9           // normpart
                         + AFFN) * 4;

    if (ws_size >= need) {
        unsigned short* pix       = (unsigned short*)d_ws;
        unsigned short* stokenBF  = pix + PIXN;
        unsigned short* refinedBF = stokenBF + STN;
        float* st_part  = (float*)(refinedBF + STN);
        float* refined  = st_part + STN * 9;
        float* normpart = refined + STN;
        float* affb     = normpart + (size_t)B_ * M_ * 9;

        k_tp  <<<B_ * HH * 12, 896, 0, stream>>>(x, pix, stokenBF);
        k_it0 <<<B_ * M_,      256, 0, stream>>>(pix, stokenBF, st_part, normpart);
        k_fold<<<B_ * M_,      256, 0, stream>>>(st_part, normpart, refined, refinedBF);
        k_aff <<<B_ * M_,      256, 0, stream>>>(pix, refinedBF, affb);
        k_out <<<B_ * HH * 12, 896, 0, stream>>>(refined, affb, out);
    } else {
        float* stoken = (float*)d_ws;
        float* raw    = stoken + STN;
        float* norm   = raw + STN;
        hipMemsetAsync(raw, 0, STN * sizeof(float), stream);
        hipMemsetAsync(norm, 0, (size_t)B_ * M_ * sizeof(float), stream);
        o_pool <<<B_ * C_ * HH, 256, 0, stream>>>(x, stoken);
        o_iter0<<<B_ * M_,      256, 0, stream>>>(x, stoken, raw, norm);
        o_final<<<B_ * M_,      256, 0, stream>>>(x, raw, norm, out);
    }
}

// Round 5
// 340.353 us; speedup vs baseline: 2.0753x; 1.3580x over previous
//
#include <hip/hip_runtime.h>
#include <cstdint>
#include <cstddef>

typedef __attribute__((ext_vector_type(8))) unsigned short us8;
typedef __attribute__((ext_vector_type(8))) short short8;
typedef __attribute__((ext_vector_type(4))) float f4v;

#define B_ 4
#define C_ 384
#define H_ 224
#define W_ 224
#define HH 28
#define WW 28
#define HW_ (H_*W_)
#define M_ (HH*WW)
#define SCALE_ 0.05103103630798288f   // 1/sqrt(384)
#define EPS_ 1e-12f

__device__ __forceinline__ unsigned short f2bf(float f) {
    union { float f; unsigned int u; } v; v.f = f;
    unsigned int r = v.u + 0x7FFFu + ((v.u >> 16) & 1u);
    return (unsigned short)(r >> 16);
}
__device__ __forceinline__ float bf2f(unsigned short h) {
    union { unsigned int u; float f; } v; v.u = ((unsigned int)h) << 16;
    return v.f;
}

// ---------------------------------------------------------------------------
// k_tp: layout transform + pool, no LDS. Block = (b, py, cgroup of 32 ch),
// 896 threads = (w 0..223) x (oct 0..3).
// ---------------------------------------------------------------------------
__global__ __launch_bounds__(896) void k_tp(const float* __restrict__ x,
                                            unsigned short* __restrict__ pix,
                                            unsigned short* __restrict__ stokenBF) {
    int bid = blockIdx.x;
    int cg = bid % 12; int t2 = bid / 12; int py = t2 % HH; int b = t2 / HH;
    int tid = threadIdx.x;
    int w = tid >> 2;          // 0..223
    int oct = tid & 3;         // 0..3
    int pxx = w >> 3, qq = w & 7;
    int cbase = cg * 32 + oct * 8;

    const float* xb = x + ((size_t)(b * C_ + cbase) * H_ + py * 8) * W_ + w;
    unsigned short* pb = pix + (((size_t)b * M_ + py * WW + pxx) * 64) * C_ + cbase;

    float v[8][8];   // [pp][j]
    #pragma unroll
    for (int j = 0; j < 8; ++j)
        #pragma unroll
        for (int pp = 0; pp < 8; ++pp)
            v[pp][j] = xb[(size_t)j * HW_ + (size_t)pp * W_];

    #pragma unroll
    for (int pp = 0; pp < 8; ++pp) {
        us8 o;
        #pragma unroll
        for (int j = 0; j < 8; ++j) o[j] = f2bf(v[pp][j]);
        *(us8*)(pb + (size_t)(pp * 8 + qq) * C_) = o;
    }

    float psum[8];
    #pragma unroll
    for (int j = 0; j < 8; ++j) {
        float s = 0.f;
        #pragma unroll
        for (int pp = 0; pp < 8; ++pp) s += v[pp][j];
        s += __shfl_xor(s, 4);
        s += __shfl_xor(s, 8);
        s += __shfl_xor(s, 16);
        psum[j] = s;
    }
    int lane = tid & 63;
    if ((lane & 28) == 0) {    // one lane per (patch, oct)
        us8 o;
        #pragma unroll
        for (int j = 0; j < 8; ++j) o[j] = f2bf(psum[j] * (1.f / 64.f));
        *(us8*)(stokenBF + ((size_t)b * M_ + py * WW + pxx) * C_ + cbase) = o;
    }
}

// ---------------------------------------------------------------------------
// QK via MFMA (m89-verified D mapping: col=lane&15, row=(lane>>4)*4+reg).
// ---------------------------------------------------------------------------
__device__ __forceinline__ f4v qk_wave(const unsigned short* __restrict__ pixP,
                                       const unsigned short* __restrict__ bfbase,
                                       int b, int py, int pxx, int mt) {
    int lane = threadIdx.x & 63;
    int n = lane & 15, g = lane >> 4;
    int yy = py + n / 3 - 1, xx = pxx + n % 3 - 1;
    bool valid = (n < 9) && yy >= 0 && yy < HH && xx >= 0 && xx < WW;
    size_t cell = valid ? ((size_t)b * M_ + (size_t)yy * WW + xx) : 0;
    const unsigned short* bp = bfbase + cell * C_ + g * 8;
    const unsigned short* ap = pixP + (size_t)(mt * 16 + n) * C_ + g * 8;
    const short8 zz = {0, 0, 0, 0, 0, 0, 0, 0};
    f4v acc = {0.f, 0.f, 0.f, 0.f};
    #pragma unroll
    for (int kt = 0; kt < 12; ++kt) {
        short8 a = *(const short8*)(ap + kt * 32);
        short8 bv = *(const short8*)(bp + kt * 32);
        if (!valid) bv = zz;
        acc = __builtin_amdgcn_mfma_f32_16x16x32_bf16(a, bv, acc, 0, 0, 0);
    }
    return acc;
}

__device__ __forceinline__ void softmax_wave(const f4v s, float aout[4]) {
    int lane = threadIdx.x & 63;
    bool coln = (lane & 15) < 9;
    float v[4], e[4], mx[4], su[4];
    #pragma unroll
    for (int r = 0; r < 4; ++r) v[r] = coln ? s[r] * SCALE_ : -3e38f;
    #pragma unroll
    for (int r = 0; r < 4; ++r) mx[r] = v[r];
    #pragma unroll
    for (int d = 1; d < 16; d <<= 1)
        #pragma unroll
        for (int r = 0; r < 4; ++r) mx[r] = fmaxf(mx[r], __shfl_xor(mx[r], d));
    #pragma unroll
    for (int r = 0; r < 4; ++r) e[r] = coln ? __expf(v[r] - mx[r]) : 0.f;
    #pragma unroll
    for (int r = 0; r < 4; ++r) su[r] = e[r];
    #pragma unroll
    for (int d = 1; d < 16; d <<= 1)
        #pragma unroll
        for (int r = 0; r < 4; ++r) su[r] += __shfl_xor(su[r], d);
    #pragma unroll
    for (int r = 0; r < 4; ++r) aout[r] = e[r] / su[r];
}

// ---------------------------------------------------------------------------
// k_it0: iteration 0. Block per (b,patch), 4 waves = 4 M-tiles.
// ---------------------------------------------------------------------------
__global__ __launch_bounds__(256) void k_it0(const unsigned short* __restrict__ pix,
                                             const unsigned short* __restrict__ stokenBF,
                                             float* __restrict__ st_part,
                                             float* __restrict__ normpart) {
    int bid = blockIdx.x;
    int m = bid % M_, b = bid / M_;
    int py = m / WW, pxx = m - py * WW;
    int tid = threadIdx.x;
    int wid = tid >> 6, lane = tid & 63;
    int n = lane & 15, g = lane >> 4;

    __shared__ float aff32[64][12];
    __shared__ float npart[4][16];

    const unsigned short* pixP = pix + (size_t)bid * 64 * C_;
    f4v s = qk_wave(pixP, stokenBF, b, py, pxx, wid);
    float a[4];
    softmax_wave(s, a);

    if (n < 9) {
        #pragma unroll
        for (int r = 0; r < 4; ++r) aff32[wid * 16 + g * 4 + r][n] = a[r];
    }
    float p = a[0] + a[1] + a[2] + a[3];
    p += __shfl_xor(p, 16);
    p += __shfl_xor(p, 32);
    if (lane < 9) npart[wid][lane] = p;
    __syncthreads();

    if (tid < 9)
        normpart[(size_t)bid * 9 + tid] =
            npart[0][tid] + npart[1][tid] + npart[2][tid] + npart[3][tid];

    for (int c = tid; c < C_; c += 256) {
        float acc9[9];
        #pragma unroll
        for (int k = 0; k < 9; ++k) acc9[k] = 0.f;
        const unsigned short* pb = pixP + c;
        for (int l = 0; l < 64; ++l) {
            float pv = bf2f(pb[(size_t)l * C_]);
            const float4* arow = (const float4*)aff32[l];
            float4 a0 = arow[0], a1 = arow[1];
            float a8 = aff32[l][8];
            acc9[0] += pv * a0.x; acc9[1] += pv * a0.y;
            acc9[2] += pv * a0.z; acc9[3] += pv * a0.w;
            acc9[4] += pv * a1.x; acc9[5] += pv * a1.y;
            acc9[6] += pv * a1.z; acc9[7] += pv * a1.w;
            acc9[8] += pv * a8;
        }
        #pragma unroll
        for (int k = 0; k < 9; ++k)
            st_part[((size_t)bid * 9 + k) * C_ + c] = acc9[k];
    }
}

// ---------------------------------------------------------------------------
// k_fold: gather-fold st_part into refined stokens (pre-divided by norm).
// ---------------------------------------------------------------------------
__global__ __launch_bounds__(256) void k_fold(const float* __restrict__ st_part,
                                              const float* __restrict__ normpart,
                                              float* __restrict__ refined,
                                              unsigned short* __restrict__ refinedBF) {
    int bid = blockIdx.x;
    int cell = bid % M_, b = bid / M_;
    int cy = cell / WW, cx = cell - cy * WW;
    int tid = threadIdx.x;

    float nsum = 0.f;
    int srcm[9]; int nsrc = 0;
    #pragma unroll
    for (int nn = 0; nn < 9; ++nn) {
        int my = cy - (nn / 3 - 1), mx = cx - (nn % 3 - 1);
        if (my >= 0 && my < HH && mx >= 0 && mx < WW) {
            int mm = my * WW + mx;
            srcm[nsrc] = mm * 9 + nn;
            nsum += normpart[(size_t)b * M_ * 9 + mm * 9 + nn];
            ++nsrc;
        }
    }
    float inv = 1.f / (nsum + EPS_);
    for (int c = tid; c < C_; c += 256) {
        float s = 0.f;
        for (int k = 0; k < nsrc; ++k)
            s += st_part[((size_t)b * M_ * 9 + srcm[k]) * C_ + c];
        float r = s * inv;
        refined[((size_t)b * M_ + cell) * C_ + c] = r;
        refinedBF[((size_t)b * M_ + cell) * C_ + c] = f2bf(r);
    }
}

// ---------------------------------------------------------------------------
// k_aff: iteration-1 affinity. Writes TRANSPOSED afft[b][py][pp][n][224]
// (w fastest) so k_out reads are wave-coalesced.
// ---------------------------------------------------------------------------
__global__ __launch_bounds__(256) void k_aff(const unsigned short* __restrict__ pix,
                                             const unsigned short* __restrict__ refinedBF,
                                             float* __restrict__ afft) {
    int bid = blockIdx.x;
    int m = bid % M_, b = bid / M_;
    int py = m / WW, pxx = m - py * WW;
    int tid = threadIdx.x;
    int wid = tid >> 6, lane = tid & 63;
    int n = lane & 15, g = lane >> 4;

    const unsigned short* pixP = pix + (size_t)bid * 64 * C_;
    f4v s = qk_wave(pixP, refinedBF, b, py, pxx, wid);
    float a[4];
    softmax_wave(s, a);

    if (n < 9) {
        #pragma unroll
        for (int r = 0; r < 4; ++r) {
            int l = wid * 16 + g * 4 + r;
            int pp = l >> 3, qq = l & 7;
            afft[((((size_t)b * HH + py) * 8 + pp) * 9 + n) * W_ + pxx * 8 + qq] = a[r];
        }
    }
}

// ---------------------------------------------------------------------------
// k_out: broadcast. Block = (b, py, cgroup of 32 ch), 896 threads =
// (ci 0..3) x (w 0..223). aff reads now fully coalesced scalar planes.
// ---------------------------------------------------------------------------
__global__ __launch_bounds__(896) void k_out(const float* __restrict__ refined,
                                             const float* __restrict__ afft,
                                             float* __restrict__ out) {
    int bid = blockIdx.x;
    int cg = bid % 12; int t2 = bid / 12; int py = t2 % HH; int b = t2 / HH;
    int c0 = cg * 32;
    int tid = threadIdx.x;
    int w = tid % 224, ci = tid / 224;
    int pxx = w >> 3;

    __shared__ float stub[3][30][33];
    for (int idx = tid; idx < 3 * 30 * 32; idx += 896) {
        int r = idx / 960; int rem = idx - r * 960;
        int xxp = rem >> 5; int cc = rem & 31;
        int yy = py + r - 1, xx = xxp - 1;
        float v = 0.f;
        if (yy >= 0 && yy < HH && xx >= 0 && xx < WW)
            v = refined[((size_t)b * M_ + yy * WW + xx) * C_ + c0 + cc];
        stub[r][xxp][cc] = v;
    }
    __syncthreads();

    const float* ab = afft + (((size_t)b * HH + py) * 8) * 9 * W_ + w;
    float* ob = out + ((size_t)(b * C_) * H_ + py * 8) * W_ + w;

    #pragma unroll
    for (int kh = 0; kh < 2; ++kh) {
        float sreg[9][4];
        #pragma unroll
        for (int nn = 0; nn < 9; ++nn)
            #pragma unroll
            for (int k = 0; k < 4; ++k)
                sreg[nn][k] = stub[nn / 3][pxx + nn % 3][ci + (kh * 4 + k) * 4];
        for (int pp = 0; pp < 8; ++pp) {
            float an[9];
            #pragma unroll
            for (int nn = 0; nn < 9; ++nn)
                an[nn] = ab[(size_t)(pp * 9 + nn) * W_];
            #pragma unroll
            for (int k = 0; k < 4; ++k) {
                float s = 0.f;
                #pragma unroll
                for (int nn = 0; nn < 9; ++nn) s += sreg[nn][k] * an[nn];
                ob[(size_t)(c0 + ci + (kh * 4 + k) * 4) * HW_ + (size_t)pp * W_] = s;
            }
        }
    }
}

// ===========================================================================
// Fallback path (round-1 kernels) if ws_size is too small.
// ===========================================================================
__global__ __launch_bounds__(256) void o_pool(const float* __restrict__ x,
                                              float* __restrict__ stoken) {
    int bid = blockIdx.x;
    int yy = bid % HH;
    int t  = bid / HH;
    int c  = t % C_;
    int b  = t / C_;
    __shared__ float colsum[W_];
    int q = threadIdx.x;
    if (q < W_) {
        const float* base = x + ((size_t)(b * C_ + c) * H_ + yy * 8) * W_ + q;
        float s = 0.f;
        #pragma unroll
        for (int p = 0; p < 8; ++p) s += base[(size_t)p * W_];
        colsum[q] = s;
    }
    __syncthreads();
    if (q < WW) {
        float s = 0.f;
        #pragma unroll
        for (int j = 0; j < 8; ++j) s += colsum[q * 8 + j];
        stoken[(((size_t)b * HH + yy) * WW + q) * C_ + c] = s * (1.f / 64.f);
    }
}

__global__ __launch_bounds__(256) void o_iter0(const float* __restrict__ x,
                                               const float* __restrict__ stoken,
                                               float* __restrict__ raw,
                                               float* __restrict__ norm) {
    int bid = blockIdx.x;
    int m = bid % M_;
    int b = bid / M_;
    int py = m / WW, pxx = m % WW;
    int tid = threadIdx.x;
    int w = tid >> 6, l = tid & 63;
    int pp = l >> 3, qq = l & 7;

    __shared__ unsigned short pixs[C_][66];
    __shared__ float sbuf[2304];
    __shared__ float aff[64][10];
    unsigned short* stub = (unsigned short*)sbuf;

    for (int idx = tid; idx < 9 * C_; idx += 256) {
        int nn = idx / C_, c = idx - nn * C_;
        int yy = py + nn / 3 - 1, xx = pxx + nn % 3 - 1;
        float v = 0.f;
        if (yy >= 0 && yy < HH && xx >= 0 && xx < WW)
            v = stoken[(((size_t)b * HH + yy) * WW + xx) * C_ + c];
        stub[idx] = f2bf(v);
    }
    __syncthreads();

    const float* pxbase = x + (size_t)b * C_ * HW_ + (size_t)(py * 8 + pp) * W_ + (pxx * 8 + qq);
    float acc[9];
    #pragma unroll
    for (int nn = 0; nn < 9; ++nn) acc[nn] = 0.f;
    int c0 = w * 96;
    #pragma unroll 4
    for (int c = c0; c < c0 + 96; ++c) {
        float pv = pxbase[(size_t)c * HW_];
        pixs[c][l] = f2bf(pv);
        #pragma unroll
        for (int nn = 0; nn < 9; ++nn) acc[nn] += pv * bf2f(stub[nn * C_ + c]);
    }
    __syncthreads();
    float* qkred = sbuf;
    #pragma unroll
    for (int nn = 0; nn < 9; ++nn) qkred[tid * 9 + nn] = acc[nn];
    __syncthreads();

    if (tid < 64) {
        float s[9];
        #pragma unroll
        for (int nn = 0; nn < 9; ++nn)
            s[nn] = (qkred[(0 * 64 + tid) * 9 + nn] + qkred[(1 * 64 + tid) * 9 + nn] +
                     qkred[(2 * 64 + tid) * 9 + nn] + qkred[(3 * 64 + tid) * 9 + nn]) * SCALE_;
        float mx = s[0];
        #pragma unroll
        for (int nn = 1; nn < 9; ++nn) mx = fmaxf(mx, s[nn]);
        float den = 0.f;
        #pragma unroll
        for (int nn = 0; nn < 9; ++nn) { float e = __expf(s[nn] - mx); den += e; s[nn] = e; }
        float inv = 1.f / den;
        #pragma unroll
        for (int nn = 0; nn < 9; ++nn) aff[tid][nn] = s[nn] * inv;
    }
    __syncthreads();

    if (tid < 9) {
        float s = 0.f;
        for (int ll = 0; ll < 64; ++ll) s += aff[ll][tid];
        int ty = py + tid / 3 - 1, tx = pxx + tid % 3 - 1;
        if (ty >= 0 && ty < HH && tx >= 0 && tx < WW)
            atomicAdd(&norm[((size_t)b * HH + ty) * WW + tx], s);
    }

    for (int c = tid; c < C_; c += 256) {
        float a2[9];
        #pragma unroll
        for (int nn = 0; nn < 9; ++nn) a2[nn] = 0.f;
        for (int ll = 0; ll < 64; ++ll) {
            float pv = bf2f(pixs[c][ll]);
            #pragma unroll
            for (int nn = 0; nn < 9; ++nn) a2[nn] += pv * aff[ll][nn];
        }
        #pragma unroll
        for (int nn = 0; nn < 9; ++nn) {
            int ty = py + nn / 3 - 1, tx = pxx + nn % 3 - 1;
            if (ty >= 0 && ty < HH && tx >= 0 && tx < WW)
                atomicAdd(&raw[(((size_t)b * HH + ty) * WW + tx) * C_ + c], a2[nn]);
        }
    }
}

__global__ __launch_bounds__(256) void o_final(const float* __restrict__ x,
                                               const float* __restrict__ raw,
                                               const float* __restrict__ norm,
                                               float* __restrict__ out) {
    int bid = blockIdx.x;
    int m = bid % M_;
    int b = bid / M_;
    int py = m / WW, pxx = m % WW;
    int tid = threadIdx.x;
    int w = tid >> 6, l = tid & 63;
    int pp = l >> 3, qq = l & 7;

    __shared__ unsigned short stub[9 * C_];
    __shared__ float qkred[4 * 64 * 9];
    __shared__ float aff[64][10];

    for (int idx = tid; idx < 9 * C_; idx += 256) {
        int nn = idx / C_, c = idx - nn * C_;
        int yy = py + nn / 3 - 1, xx = pxx + nn % 3 - 1;
        float v = 0.f;
        if (yy >= 0 && yy < HH && xx >= 0 && xx < WW) {
            size_t cell = ((size_t)b * HH + yy) * WW + xx;
            v = raw[cell * C_ + c] / (norm[cell] + EPS_);
        }
        stub[idx] = f2bf(v);
    }
    __syncthreads();

    const float* pxbase = x + (size_t)b * C_ * HW_ + (size_t)(py * 8 + pp) * W_ + (pxx * 8 + qq);
    float acc[9];
    #pragma unroll
    for (int nn = 0; nn < 9; ++nn) acc[nn] = 0.f;
    int c0 = w * 96;
    #pragma unroll 4
    for (int c = c0; c < c0 + 96; ++c) {
        float pv = pxbase[(size_t)c * HW_];
        #pragma unroll
        for (int nn = 0; nn < 9; ++nn) acc[nn] += pv * bf2f(stub[nn * C_ + c]);
    }
    #pragma unroll
    for (int nn = 0; nn < 9; ++nn) qkred[tid * 9 + nn] = acc[nn];
    __syncthreads();

    if (tid < 64) {
        float s[9];
        #pragma unroll
        for (int nn = 0; nn < 9; ++nn)
            s[nn] = (qkred[(0 * 64 + tid) * 9 + nn] + qkred[(1 * 64 + tid) * 9 + nn] +
                     qkred[(2 * 64 + tid) * 9 + nn] + qkred[(3 * 64 + tid) * 9 + nn]) * SCALE_;
        float mx = s[0];
        #pragma unroll
        for (int nn = 1; nn < 9; ++nn) mx = fmaxf(mx, s[nn]);
        float den = 0.f;
        #pragma unroll
        for (int nn = 0; nn < 9; ++nn) { float e = __expf(s[nn] - mx); den += e; s[nn] = e; }
        float inv = 1.f / den;
        #pragma unroll
        for (int nn = 0; nn < 9; ++nn) aff[tid][nn] = s[nn] * inv;
    }
    __syncthreads();

    float areg[9];
    #pragma unroll
    for (int nn = 0; nn < 9; ++nn) areg[nn] = aff[l][nn];
    float* obase = out + (size_t)b * C_ * HW_ + (size_t)(py * 8 + pp) * W_ + (pxx * 8 + qq);
    #pragma unroll 4
    for (int c = c0; c < c0 + 96; ++c) {
        float v = 0.f;
        #pragma unroll
        for (int nn = 0; nn < 9; ++nn) v += bf2f(stub[nn * C_ + c]) * areg[nn];
        obase[(size_t)c * HW_] = v;
    }
}

extern "C" void kernel_launch(void* const* d_in, const int* in_sizes, int n_in,
                              void* d_out, int out_size, void* d_ws, size_t ws_size,
                              hipStream_t stream) {
    const float* x = (const float*)d_in[0];
    float* out = (float*)d_out;

    const size_t PIXN = (size_t)B_ * M_ * 64 * C_;      // bf16 elements
    const size_t STN  = (size_t)B_ * M_ * C_;           // elements per stoken set
    const size_t AFFN = (size_t)B_ * HH * 8 * 9 * W_;   // fp32 elements (transposed aff)
    const size_t need = PIXN * 2 + STN * 2 + STN * 2
                      + (STN * 10 + (size_t)B_ * M_ * 9 + AFFN) * 4;

    if (ws_size >= need) {
        unsigned short* pix       = (unsigned short*)d_ws;
        unsigned short* stokenBF  = pix + PIXN;
        unsigned short* refinedBF = stokenBF + STN;
        float* st_part  = (float*)(refinedBF + STN);
        float* refined  = st_part + STN * 9;
        float* normpart = refined + STN;
        float* afft     = normpart + (size_t)B_ * M_ * 9;

        k_tp  <<<B_ * HH * 12, 896, 0, stream>>>(x, pix, stokenBF);
        k_it0 <<<B_ * M_,      256, 0, stream>>>(pix, stokenBF, st_part, normpart);
        k_fold<<<B_ * M_,      256, 0, stream>>>(st_part, normpart, refined, refinedBF);
        k_aff <<<B_ * M_,      256, 0, stream>>>(pix, refinedBF, afft);
        k_out <<<B_ * HH * 12, 896, 0, stream>>>(refined, afft, out);
    } else {
        float* stoken = (float*)d_ws;
        float* raw    = stoken + STN;
        float* norm   = raw + STN;
        hipMemsetAsync(raw, 0, STN * sizeof(float), stream);
        hipMemsetAsync(norm, 0, (size_t)B_ * M_ * sizeof(float), stream);
        o_pool <<<B_ * C_ * HH, 256, 0, stream>>>(x, stoken);
        o_iter0<<<B_ * M_,      256, 0, stream>>>(x, stoken, raw, norm);
        o_final<<<B_ * M_,      256, 0, stream>>>(x, raw, norm, out);
    }
}